// Round 6
// baseline (186.389 us; speedup 1.0000x reference)
//
#include <hip/hip_runtime.h>

// BERT lattice embedding: ragged segment mean-pool.
// hidden: [B,S,H] f32, word_ids: [B,S] i32 (non-decreasing per sample),
// out: [B,T,H] f32 = mean over contiguous run of pieces (zeros if empty).
//
// R5: copy-kernel shape. Kernel A builds a packed (start|cnt<<16) table.
// Kernel B: one wave owns 8 consecutive output rows (800 blocks x 4 waves,
// long-lived). One vector load fetches all 8 table entries; readlane -> SGPRs
// so all run logic is scalar. Rows processed 2/iter with a branch-free
// cnt<=2 fast path: load first+last piece rows unconditionally (cnt==1 ->
// same row, L1 hit) and mask; 12 independent 16B loads back-to-back per
// iteration (12KB/wave in flight). cnt>=3 middles: rare (~13%) scalar branch.

#define BB 64
#define SS 512
#define HH 768
#define TT 400
#define H4 (HH / 4)              // 192 float4 per row
#define RPW 8                    // rows per wave (TT % RPW == 0 -> same b)
#define WPB 4                    // waves per block
#define NBLK (BB * TT / (WPB * RPW))   // 800

typedef float f32x4 __attribute__((ext_vector_type(4)));

// ---------- Kernel A: per-(b,t) run table ----------
__global__ __launch_bounds__(256) void build_table_kernel(
    const int* __restrict__ word_ids,
    int* __restrict__ table)          // [BB*TT] packed: start | (cnt<<16)
{
    __shared__ int wid[SS];
    __shared__ int sstart[TT];
    __shared__ int send[TT];

    const int b   = blockIdx.x;
    const int tid = threadIdx.x;

    if (tid < SS / 4) {
        reinterpret_cast<int4*>(wid)[tid] =
            reinterpret_cast<const int4*>(word_ids + b * SS)[tid];
    }
    for (int t = tid; t < TT; t += 256) { sstart[t] = 0; send[t] = 0; }
    __syncthreads();

    for (int s = tid; s < SS; s += 256) {
        const int w = wid[s];                       // w in [0, TT)
        if (s == 0      || wid[s - 1] != w) sstart[w] = s;
        if (s == SS - 1 || wid[s + 1] != w) send[w]   = s + 1;
    }
    __syncthreads();

    for (int t = tid; t < TT; t += 256) {
        const int st  = sstart[t];
        const int cnt = send[t] - st;               // empty word: 0
        table[b * TT + t] = st | (cnt << 16);
    }
}

// ---------- Kernel B: 8 rows per wave, pipelined ----------
__global__ __launch_bounds__(256) void pool_kernel(
    const float* __restrict__ hidden,
    const int* __restrict__ table,
    float* __restrict__ out)
{
    const int wave    = threadIdx.x >> 6;
    const int lane    = threadIdx.x & 63;
    const int base_bt = (blockIdx.x * WPB + wave) * RPW;
    const int b       = base_bt / TT;               // uniform (TT % RPW == 0)

    // All 8 packed entries in one load (one cache line); lanes 0..7 hold them.
    const int mypack = table[base_bt + (lane & (RPW - 1))];

    const f32x4* hb = reinterpret_cast<const f32x4*>(hidden) + (size_t)b * SS * H4;
    f32x4*       ob = reinterpret_cast<f32x4*>(out) + (size_t)base_bt * H4;

    #pragma unroll
    for (int j = 0; j < RPW; j += 2) {
        const int p0 = __builtin_amdgcn_readlane(mypack, j);       // SGPR
        const int p1 = __builtin_amdgcn_readlane(mypack, j + 1);   // SGPR
        const int s0 = p0 & 0xFFFF, c0 = p0 >> 16;
        const int s1 = p1 & 0xFFFF, c1 = p1 >> 16;
        const int e0 = s0 + ((c0 > 1) ? (c0 - 1) : 0);   // last piece row
        const int e1 = s1 + ((c1 > 1) ? (c1 - 1) : 0);

        const f32x4* r0a = hb + (size_t)s0 * H4;
        const f32x4* r0b = hb + (size_t)e0 * H4;
        const f32x4* r1a = hb + (size_t)s1 * H4;
        const f32x4* r1b = hb + (size_t)e1 * H4;

        // 12 independent loads, nothing between them (branch-free).
        f32x4 va0 = r0a[lane], va1 = r0a[lane + 64], va2 = r0a[lane + 128];
        f32x4 vb0 = r0b[lane], vb1 = r0b[lane + 64], vb2 = r0b[lane + 128];
        f32x4 wa0 = r1a[lane], wa1 = r1a[lane + 64], wa2 = r1a[lane + 128];
        f32x4 wb0 = r1b[lane], wb1 = r1b[lane + 64], wb2 = r1b[lane + 128];

        const float ka = (c0 >= 1) ? 1.f : 0.f;   // first row counts iff cnt>=1
        const float kb = (c0 >= 2) ? 1.f : 0.f;   // last row counts iff cnt>=2
        const float la = (c1 >= 1) ? 1.f : 0.f;
        const float lb = (c1 >= 2) ? 1.f : 0.f;

        f32x4 A0 = va0 * ka + vb0 * kb;
        f32x4 A1 = va1 * ka + vb1 * kb;
        f32x4 A2 = va2 * ka + vb2 * kb;
        f32x4 B0 = wa0 * la + wb0 * lb;
        f32x4 B1 = wa1 * la + wb1 * lb;
        f32x4 B2 = wa2 * la + wb2 * lb;

        if (c0 > 2) {                               // scalar-uniform, ~13%
            const f32x4* p = hb + (size_t)(s0 + 1) * H4;
            for (int i = 0; i < c0 - 2; ++i, p += H4) {
                A0 += p[lane]; A1 += p[lane + 64]; A2 += p[lane + 128];
            }
        }
        if (c1 > 2) {
            const f32x4* p = hb + (size_t)(s1 + 1) * H4;
            for (int i = 0; i < c1 - 2; ++i, p += H4) {
                B0 += p[lane]; B1 += p[lane + 64]; B2 += p[lane + 128];
            }
        }

        const float i0 = 1.f / (float)((c0 > 1) ? c0 : 1);
        const float i1 = 1.f / (float)((c1 > 1) ? c1 : 1);
        A0 *= i0; A1 *= i0; A2 *= i0;
        B0 *= i1; B1 *= i1; B2 *= i1;

        f32x4* o0 = ob + (size_t)j * H4;
        f32x4* o1 = ob + (size_t)(j + 1) * H4;
        __builtin_nontemporal_store(A0, &o0[lane]);
        __builtin_nontemporal_store(A1, &o0[lane + 64]);
        __builtin_nontemporal_store(A2, &o0[lane + 128]);
        __builtin_nontemporal_store(B0, &o1[lane]);
        __builtin_nontemporal_store(B1, &o1[lane + 64]);
        __builtin_nontemporal_store(B2, &o1[lane + 128]);
    }
}

extern "C" void kernel_launch(void* const* d_in, const int* in_sizes, int n_in,
                              void* d_out, int out_size, void* d_ws, size_t ws_size,
                              hipStream_t stream) {
    (void)in_sizes; (void)n_in; (void)ws_size; (void)out_size;
    const float* hidden   = (const float*)d_in[0];
    const int*   word_ids = (const int*)d_in[1];
    float*       out      = (float*)d_out;
    int*         table    = (int*)d_ws;             // BB*TT*4 = 100 KB

    build_table_kernel<<<dim3(BB), dim3(256), 0, stream>>>(word_ids, table);
    pool_kernel<<<dim3(NBLK), dim3(256), 0, stream>>>(hidden, table, out);
}